// Round 7
// baseline (543.290 us; speedup 1.0000x reference)
//
#include <hip/hip_runtime.h>
#include <math.h>
#include <stdio.h>

// EdgewiseMSA: B=2, N=1024, DIM=512, H=8, DK=64, HIDDEN=16
// Full pipeline, bf16 MFMA GEMMs (A @ B^T form), f32 elementwise.
// Gating saga: R3 full-unroll -> 256 VGPR (occ 12%); R4 cap -> 32 VGPR 10GB
// spill; R5 cap(64) -> 5GB spill; R6 o-loop unroll 1 -> healthy (16 VGPR, no
// spill) but zero ILP: 219us vs ~64us arith floor. R7: o-loop unroll 4 —
// 4 gelu chains live (~50 VGPR), TRANS/VALU overlap, weights ds_read amortized.

typedef unsigned short u16;
typedef __attribute__((ext_vector_type(8))) short short8;
typedef __attribute__((ext_vector_type(4))) short short4v;
typedef __attribute__((ext_vector_type(4))) float f32x4;

#define DEVI static __device__ __forceinline__

DEVI float bf2f(u16 u){ union{unsigned v; float f;} x; x.v = ((unsigned)u)<<16u; return x.f; }
DEVI u16 f2bf(float f){ union{float f; unsigned v;} x; x.f=f; unsigned r = x.v + 0x7FFFu + ((x.v>>16)&1u); return (u16)(r>>16); }

// fast sigmoid: 1/(1+e^-x) via v_exp_f32 + v_rcp_f32
DEVI float fsigmoid(float x){
  float e = __expf(-x);
  return __builtin_amdgcn_rcpf(1.f + e);
}

enum { EPI_F32=0, EPI_BF16=1, EPI_LOGBF16=2, EPI_BF16T=3, EPI_QKV=4, EPI_Y=5, EPI_YADD=6 };

// C[r][c] = sum_k A[r][k] * Bt[c][k].  BMxBN tile, 4 waves (WR x WC), BK=32.
template<int BM,int BN,int WR,int WC,int EPI>
__global__ __launch_bounds__(256) void gemm_bt(
    const u16* __restrict__ A, const u16* __restrict__ B,
    void* __restrict__ p0, void* __restrict__ p1, void* __restrict__ p2,
    const float* __restrict__ logit,
    int K, int lda, int ldb,
    long long sA, long long sB, long long sC, int ldc)
{
  constexpr int WM = BM/WR, WN = BN/WC;
  constexpr int FM = WM/16, FN = WN/16;
  constexpr int BK = 32, LDSP = BK+8;
  __shared__ u16 As[BM][LDSP];
  __shared__ u16 Bs[BN][LDSP];
  const int z = blockIdx.z;
  const u16* Ap = A + (long long)z*sA;
  const u16* Bp = B + (long long)z*sB;
  const int r0 = blockIdx.y*BM, c0 = blockIdx.x*BN;
  const int tid = threadIdx.x;
  const int wave = tid>>6, lane = tid&63;
  const int wr = (wave/WC)*WM, wc = (wave%WC)*WN;
  const int fr = lane&15, fk = lane>>4;

  f32x4 acc[FM][FN] = {};

  for (int k0=0; k0<K; k0+=BK){
    __syncthreads();
    #pragma unroll
    for (int i=0;i<(BM*4)/256;i++){
      int idx = tid + i*256;
      int row = idx>>2, col = (idx&3)*8;
      *(short8*)&As[row][col] = *(const short8*)&Ap[(long long)(r0+row)*lda + k0 + col];
    }
    #pragma unroll
    for (int i=0;i<(BN*4)/256;i++){
      int idx = tid + i*256;
      int row = idx>>2, col = (idx&3)*8;
      *(short8*)&Bs[row][col] = *(const short8*)&Bp[(long long)(c0+row)*ldb + k0 + col];
    }
    __syncthreads();
    short8 af[FM], bfr[FN];
    #pragma unroll
    for (int m=0;m<FM;m++) af[m] = *(const short8*)&As[wr + m*16 + fr][fk*8];
    #pragma unroll
    for (int n=0;n<FN;n++) bfr[n] = *(const short8*)&Bs[wc + n*16 + fr][fk*8];
    #pragma unroll
    for (int m=0;m<FM;m++)
      #pragma unroll
      for (int n=0;n<FN;n++)
        acc[m][n] = __builtin_amdgcn_mfma_f32_16x16x32_bf16(af[m], bfr[n], acc[m][n], 0,0,0);
  }

  float yscale = 0.f;
  if constexpr (EPI==EPI_YADD) yscale = 1.f/(1.f+expf(-logit[0]));

  #pragma unroll
  for (int m=0;m<FM;m++)
   #pragma unroll
   for (int n=0;n<FN;n++)
    #pragma unroll
    for (int j=0;j<4;j++){
      int r = r0 + wr + m*16 + fk*4 + j;
      int c = c0 + wc + n*16 + fr;
      float v = acc[m][n][j];
      if constexpr (EPI==EPI_F32){
        ((float*)p0)[(long long)z*sC + (long long)r*ldc + c] = v;
      } else if constexpr (EPI==EPI_BF16){
        ((u16*)p0)[(long long)z*sC + (long long)r*ldc + c] = f2bf(v);
      } else if constexpr (EPI==EPI_LOGBF16){
        ((u16*)p0)[(long long)z*sC + (long long)r*ldc + c] = f2bf(__logf(v + 1e-6f));
      } else if constexpr (EPI==EPI_BF16T){
        ((u16*)p0)[(long long)z*sC + (long long)c*ldc + r] = f2bf(v);
      } else if constexpr (EPI==EPI_QKV){
        // r in [0,2048): token; c in [0,1536): (which,h,d)
        int b = r>>10, n_ = r&1023;
        int which = c>>9, h = (c>>6)&7, d = c&63;
        long long bh = (long long)b*8 + h;
        if (which==0)      ((u16*)p0)[(bh*1024 + n_)*64 + d] = f2bf(v*0.125f); // q, scale folded
        else if (which==1) ((u16*)p1)[(bh*1024 + n_)*64 + d] = f2bf(v);        // k natural [n][d]
        else               ((u16*)p2)[(bh*64 + d)*1024 + n_] = f2bf(v);        // v transposed [d][n]
      } else if constexpr (EPI==EPI_Y){
        int b = z>>3, h = z&7;
        ((float*)p0)[((long long)(b*1024 + r))*512 + h*64 + c] = v;
      } else if constexpr (EPI==EPI_YADD){
        int b = z>>3, h = z&7;
        ((float*)p0)[((long long)(b*1024 + r))*512 + h*64 + c] += yscale*v;
      }
    }
}

// row softmax over 1024 cols; src f32 or bf16; dst bf16
template<int SRC_BF16>
__global__ __launch_bounds__(256) void softmax_rows(const void* __restrict__ Sv, u16* __restrict__ A)
{
  const long long row = blockIdx.x;
  const int tid = threadIdx.x;
  float v[4];
  if constexpr (SRC_BF16){
    const u16* s = (const u16*)Sv + row*1024;
    short4v x = *(const short4v*)&s[tid*4];
    #pragma unroll
    for (int i=0;i<4;i++) v[i] = bf2f((u16)x[i]);
  } else {
    const float* s = (const float*)Sv + row*1024;
    f32x4 x = *(const f32x4*)&s[tid*4];
    #pragma unroll
    for (int i=0;i<4;i++) v[i] = x[i];
  }
  __shared__ float red[4];
  float m = fmaxf(fmaxf(v[0],v[1]),fmaxf(v[2],v[3]));
  #pragma unroll
  for (int off=32; off>0; off>>=1) m = fmaxf(m, __shfl_xor(m, off, 64));
  if ((tid&63)==0) red[tid>>6] = m;
  __syncthreads();
  m = fmaxf(fmaxf(red[0],red[1]),fmaxf(red[2],red[3]));
  float e[4], sum=0.f;
  #pragma unroll
  for (int i=0;i<4;i++){ e[i] = __expf(v[i]-m); sum += e[i]; }
  #pragma unroll
  for (int off=32; off>0; off>>=1) sum += __shfl_xor(sum, off, 64);
  __syncthreads();
  if ((tid&63)==0) red[tid>>6] = sum;
  __syncthreads();
  float inv = 1.f/(red[0]+red[1]+red[2]+red[3]);
  u16* a = A + row*1024;
  short4v o;
  #pragma unroll
  for (int i=0;i<4;i++) o[i] = (short)f2bf(e[i]*inv);
  *(short4v*)&a[tid*4] = o;
}

// 1024x1024 bf16 transpose per z
__global__ __launch_bounds__(256) void transpose_bf16(const u16* __restrict__ in, u16* __restrict__ out)
{
  __shared__ u16 tile[32][33];
  const long long base = (long long)blockIdx.z*1024*1024;
  const int xb = blockIdx.x*32, yb = blockIdx.y*32;
  const int tx = threadIdx.x&31, ty = threadIdx.x>>5;
  #pragma unroll
  for (int rr=0;rr<4;rr++){
    int i = ty + rr*8;
    tile[i][tx] = in[base + (long long)(yb+i)*1024 + xb+tx];
  }
  __syncthreads();
  #pragma unroll
  for (int rr=0;rr<4;rr++){
    int i = ty + rr*8;
    out[base + (long long)(xb+i)*1024 + yb+tx] = tile[tx][i];
  }
}

__global__ __launch_bounds__(256) void cast_f32_bf16(const float* __restrict__ in, u16* __restrict__ out, int n4)
{
  int i = blockIdx.x*256 + threadIdx.x;
  if (i < n4){
    f32x4 x = ((const f32x4*)in)[i];
    short4v o;
    #pragma unroll
    for (int j=0;j<4;j++) o[j] = (short)f2bf(x[j]);
    ((short4v*)out)[i] = o;
  }
}

// out[c][r] = bf16(in[r][c]); in: rows x cols (f32)
__global__ __launch_bounds__(256) void castT_f32_bf16(const float* __restrict__ in, u16* __restrict__ out, int rows, int cols)
{
  __shared__ float tile[32][33];
  const int cb = blockIdx.x*32, rb = blockIdx.y*32;
  const int tx = threadIdx.x&31, ty = threadIdx.x>>5;
  #pragma unroll
  for (int rr=0;rr<4;rr++){
    int i = ty + rr*8;
    tile[i][tx] = in[(long long)(rb+i)*cols + cb+tx];
  }
  __syncthreads();
  #pragma unroll
  for (int rr=0;rr<4;rr++){
    int i = ty + rr*8;
    out[(long long)(cb+i)*rows + rb+tx] = f2bf(tile[tx][i]);
  }
}

// gating + Smix -> Smix bf16. o-loop unroll 4: four gelu chains in flight
// (R6's unroll 1 was issue-bound at 219us; full unroll spilled in R3/R4/R5).
__global__ __launch_bounds__(256) void gating_kernel(
    const u16* __restrict__ S0, const u16* __restrict__ S1,
    const u16* __restrict__ CR, const u16* __restrict__ CL,
    const float* __restrict__ w1, const float* __restrict__ b1,
    const float* __restrict__ w2, const float* __restrict__ b2,
    u16* __restrict__ Smix)
{
  __shared__ float t0[32][33], t1[32][33], t0t[32][33], t1t[32][33];
  __shared__ float sw1[96], sb1[16], sw2[64], sb2[4];
  const int tid = threadIdx.x;
  if (tid < 96) sw1[tid] = w1[tid];
  if (tid < 16) sb1[tid] = b1[tid];
  if (tid < 64) sw2[tid] = w2[tid];
  if (tid < 4)  sb2[tid] = b2[tid];
  const long long base = (long long)blockIdx.z*1024*1024;
  const int rb = blockIdx.y*32, cb = blockIdx.x*32;
  const int tx = tid&31, ty = tid>>5;
  #pragma unroll
  for (int rr=0;rr<4;rr++){
    int i = ty + rr*8;
    t0 [i][tx] = bf2f(S0[base + (long long)(rb+i)*1024 + cb+tx]);
    t1 [i][tx] = bf2f(S1[base + (long long)(rb+i)*1024 + cb+tx]);
    t0t[i][tx] = bf2f(S0[base + (long long)(cb+i)*1024 + rb+tx]);
    t1t[i][tx] = bf2f(S1[base + (long long)(cb+i)*1024 + rb+tx]);
  }
  __syncthreads();
  #pragma unroll 1
  for (int rr=0;rr<4;rr++){
    int i = ty + rr*8;
    float s0  = t0[i][tx], s1v = t1[i][tx];
    float s0t = t0t[tx][i], s1t = t1t[tx][i];
    long long off = base + (long long)(rb+i)*1024 + cb+tx;
    float cr = bf2f(CR[off]), cl = bf2f(CL[off]);
    float a0 = sb2[0], a1 = sb2[1], a2 = sb2[2], a3 = sb2[3];
    #pragma unroll 4
    for (int o=0;o<16;o++){
      float xx = sb1[o] + sw1[o*6+0]*s0 + sw1[o*6+1]*s1v + sw1[o*6+2]*s0t
               + sw1[o*6+3]*s1t + sw1[o*6+4]*cr + sw1[o*6+5]*cl;
      // gelu(x) = x * sigmoid(2*0.79788456*(x + 0.044715 x^3))
      float z = 1.5957691216057308f*(xx + 0.044715f*xx*xx*xx);
      float hh = xx * fsigmoid(z);
      a0 += sw2[o]*hh; a1 += sw2[16+o]*hh; a2 += sw2[32+o]*hh; a3 += sw2[48+o]*hh;
    }
    float g0 = fsigmoid(a0), g1 = fsigmoid(a1), g2 = fsigmoid(a2), g3 = fsigmoid(a3);
    float mx = fmaxf(s0,s1v);
    float e = __expf(-fabsf(s0-s1v));
    float lse = mx + __logf(1.f + e);
    float smix = s0 + g0*s1v + g1*(lse-s0) - g2*(0.5f*s1v) + g3*cr;
    Smix[off] = f2bf(smix);
  }
}

extern "C" void kernel_launch(void* const* d_in, const int* in_sizes, int n_in,
                              void* d_out, int out_size, void* d_ws, size_t ws_size,
                              hipStream_t stream)
{
  const float* x     = (const float*)d_in[0];
  const float* Wqkv0 = (const float*)d_in[1];
  const float* Wqkv1 = (const float*)d_in[2];
  const float* Wproj = (const float*)d_in[3];
  const float* c1w   = (const float*)d_in[4];
  const float* c1b   = (const float*)d_in[5];
  const float* c2w   = (const float*)d_in[6];
  const float* c2b   = (const float*)d_in[7];
  const float* logit = (const float*)d_in[8];

  char* ws = (char*)d_ws;
  size_t off = 0;
  auto alloc = [&](size_t bytes)->char*{ char* p = ws + off; off = (off + bytes + 255) & ~(size_t)255; return p; };

  const long long NN16 = 16LL*1024*1024;
  u16* xb  = (u16*)alloc(2048LL*512*2);
  u16* w0T = (u16*)alloc(1536LL*512*2);
  u16* w1T = (u16*)alloc(1536LL*512*2);
  u16* wpT = (u16*)alloc(512LL*512*2);
  u16* q0  = (u16*)alloc(16LL*1024*64*2);
  u16* k0  = (u16*)alloc(16LL*1024*64*2);
  u16* v0T = (u16*)alloc(16LL*1024*64*2);
  u16* q1  = (u16*)alloc(16LL*1024*64*2);
  u16* k1  = (u16*)alloc(16LL*1024*64*2);
  u16* v1T = (u16*)alloc(16LL*1024*64*2);
  u16* S0b = (u16*)alloc(NN16*2);   // reused as Ab after gating
  u16* S1b = (u16*)alloc(NN16*2);
  u16* A0  = (u16*)alloc(NN16*2);
  u16* A1  = (u16*)alloc(NN16*2);
  u16* A0T = (u16*)alloc(NN16*2);   // reused as CR after CL GEMM
  u16* A1T = (u16*)alloc(NN16*2);   // reused as Smix after CR GEMM
  u16* CL  = (u16*)alloc(NN16*2);
  u16* tT  = (u16*)alloc(16LL*64*1024*2);
  float* Y = (float*)alloc(2048LL*512*4);
  u16* Yb  = (u16*)alloc(2048LL*512*2);

  u16* CR   = A0T;   // A0T dead after CL GEMM (which runs first)
  u16* Smix = A1T;   // A1T dead after CR GEMM
  u16* Ab   = S0b;   // S0b dead after gating

  if (off > ws_size){
    fprintf(stderr, "kernel_launch: ws too small: need %zu have %zu\n", off, ws_size);
    return;
  }

  dim3 blk(256);

  // 1. input casts / transposed weight casts
  cast_f32_bf16<<<dim3(262144/256), blk, 0, stream>>>(x, xb, 262144);
  castT_f32_bf16<<<dim3(48,16), blk, 0, stream>>>(Wqkv0, w0T, 512, 1536);
  castT_f32_bf16<<<dim3(48,16), blk, 0, stream>>>(Wqkv1, w1T, 512, 1536);
  castT_f32_bf16<<<dim3(16,16), blk, 0, stream>>>(Wproj, wpT, 512, 512);

  // 2. QKV projections (scatter epilogue; q scaled by 1/sqrt(DK))
  gemm_bt<128,128,2,2,EPI_QKV><<<dim3(12,16,1), blk, 0, stream>>>(
      xb, w0T, q0, k0, v0T, nullptr, 512, 512, 512, 0,0, 0,0);
  gemm_bt<128,128,2,2,EPI_QKV><<<dim3(12,16,1), blk, 0, stream>>>(
      xb, w1T, q1, k1, v1T, nullptr, 512, 512, 512, 0,0, 0,0);

  // 3. S0 = q0 k0^T, S1 = q1 k1^T (scaled already)  -> bf16
  gemm_bt<128,128,2,2,EPI_BF16><<<dim3(8,8,16), blk, 0, stream>>>(
      q0, k0, S0b, nullptr, nullptr, nullptr, 64, 64, 64, 65536,65536, 1048576, 1024);
  gemm_bt<128,128,2,2,EPI_BF16><<<dim3(8,8,16), blk, 0, stream>>>(
      q1, k1, S1b, nullptr, nullptr, nullptr, 64, 64, 64, 65536,65536, 1048576, 1024);

  // 4. A0 = softmax(S0), A1 = softmax(S1)
  softmax_rows<1><<<dim3(16384), blk, 0, stream>>>(S0b, A0);
  softmax_rows<1><<<dim3(16384), blk, 0, stream>>>(S1b, A1);

  // 5. transposes for C GEMMs
  transpose_bf16<<<dim3(32,32,16), blk, 0, stream>>>(A0, A0T);
  transpose_bf16<<<dim3(32,32,16), blk, 0, stream>>>(A1, A1T);

  // 6. Cli = log(A1@A0 + eps) FIRST (frees A0T), then Cri = log(A0@A1 + eps) into CR(=A0T)
  gemm_bt<128,128,2,2,EPI_LOGBF16><<<dim3(8,8,16), blk, 0, stream>>>(
      A1, A0T, CL, nullptr, nullptr, nullptr, 1024, 1024, 1024, 1048576,1048576, 1048576, 1024);
  gemm_bt<128,128,2,2,EPI_LOGBF16><<<dim3(8,8,16), blk, 0, stream>>>(
      A0, A1T, CR, nullptr, nullptr, nullptr, 1024, 1024, 1024, 1048576,1048576, 1048576, 1024);

  // 7. gating conv chain -> Smix (bf16, into A1T space)
  gating_kernel<<<dim3(32,32,16), blk, 0, stream>>>(S0b, S1b, CR, CL, c1w, c1b, c2w, c2b, Smix);

  // 8. A = softmax(Smix) -> bf16 (into Ab = S0b space)
  softmax_rows<1><<<dim3(16384), blk, 0, stream>>>(Smix, Ab);

  // 9. t = A1 @ v1 (stored transposed tT[d][n]);  y_base = A @ v0;  y += sig*A0@t
  //    64x64 tiles -> 256 blocks each (fills all CUs)
  gemm_bt<64,64,2,2,EPI_BF16T><<<dim3(1,16,16), blk, 0, stream>>>(
      A1, v1T, tT, nullptr, nullptr, nullptr, 1024, 1024, 1024, 1048576,65536, 65536, 1024);
  gemm_bt<64,64,2,2,EPI_Y><<<dim3(1,16,16), blk, 0, stream>>>(
      Ab, v0T, Y, nullptr, nullptr, nullptr, 1024, 1024, 1024, 1048576,65536, 0, 0);
  gemm_bt<64,64,2,2,EPI_YADD><<<dim3(1,16,16), blk, 0, stream>>>(
      A0, tT, Y, nullptr, nullptr, logit, 1024, 1024, 1024, 1048576,65536, 0, 0);

  // 10. out = Y @ Wproj (64x64 tiles -> 256 blocks)
  cast_f32_bf16<<<dim3(262144/256), blk, 0, stream>>>(Y, Yb, 262144);
  gemm_bt<64,64,2,2,EPI_F32><<<dim3(8,32,1), blk, 0, stream>>>(
      Yb, wpT, d_out, nullptr, nullptr, nullptr, 512, 512, 512, 0,0, 0, 512);

  (void)in_sizes; (void)n_in; (void)out_size;
}

// Round 8
// 516.837 us; speedup vs baseline: 1.0512x; 1.0512x over previous
//
#include <hip/hip_runtime.h>
#include <math.h>
#include <stdio.h>

// EdgewiseMSA: B=2, N=1024, DIM=512, H=8, DK=64, HIDDEN=16
// R8: (1) gating weights read as wave-uniform GLOBAL loads -> s_load/SGPR
//     (R7 diagnosis: 96 ds_read_b32 weight broadcasts per element = 238us,
//     matches the observed 219us; arithmetic itself is ~3us).
//     (2) gemm_bt: m97 structure -- BK=64, linear [BM][64] LDS,
//     global_load_lds width=16 staging (verified 334->874 TF ladder step).

typedef unsigned short u16;
typedef __attribute__((ext_vector_type(8))) short short8;
typedef __attribute__((ext_vector_type(4))) short short4v;
typedef __attribute__((ext_vector_type(4))) float f32x4;

#define DEVI static __device__ __forceinline__

DEVI float bf2f(u16 u){ union{unsigned v; float f;} x; x.v = ((unsigned)u)<<16u; return x.f; }
DEVI u16 f2bf(float f){ union{float f; unsigned v;} x; x.f=f; unsigned r = x.v + 0x7FFFu + ((x.v>>16)&1u); return (u16)(r>>16); }

DEVI float fsigmoid(float x){
  float e = __expf(-x);
  return __builtin_amdgcn_rcpf(1.f + e);
}

DEVI void gload_lds16(const u16* gptr, u16* lptr){
  __builtin_amdgcn_global_load_lds(
      (const __attribute__((address_space(1))) void*)gptr,
      (__attribute__((address_space(3))) void*)lptr,
      16, 0, 0);
}

enum { EPI_F32=0, EPI_BF16=1, EPI_LOGBF16=2, EPI_BF16T=3, EPI_QKV=4, EPI_Y=5, EPI_YADD=6 };

// C[r][c] = sum_k A[r][k] * Bt[c][k].  BMxBN tile, 4 waves (WR x WC), BK=64,
// global_load_lds staging into linear [BM][64] LDS (m97 structure).
template<int BM,int BN,int WR,int WC,int EPI>
__global__ __launch_bounds__(256) void gemm_bt(
    const u16* __restrict__ A, const u16* __restrict__ B,
    void* __restrict__ p0, void* __restrict__ p1, void* __restrict__ p2,
    const float* __restrict__ logit,
    int K, int lda, int ldb,
    long long sA, long long sB, long long sC, int ldc)
{
  constexpr int WM = BM/WR, WN = BN/WC;
  constexpr int FM = WM/16, FN = WN/16;
  constexpr int BK = 64;
  __shared__ u16 As[BM][BK];
  __shared__ u16 Bs[BN][BK];
  const int z = blockIdx.z;
  const u16* Ap = A + (long long)z*sA;
  const u16* Bp = B + (long long)z*sB;
  const int r0 = blockIdx.y*BM, c0 = blockIdx.x*BN;
  const int tid = threadIdx.x;
  const int wave = tid>>6, lane = tid&63;
  const int wr = (wave/WC)*WM, wc = (wave%WC)*WN;
  const int fr = lane&15, fk = lane>>4;
  const int l8 = lane>>3, l7 = lane&7;   // staging: 8 lanes per row, 8 bf16 per lane

  f32x4 acc[FM][FN] = {};

  for (int k0=0; k0<K; k0+=BK){
    __syncthreads();
    // stage A: (BM/8) wave-instructions, each covers 8 rows x 64 cols
    #pragma unroll
    for (int i=0;i<BM/32;i++){
      int ins = wave + 4*i;
      int row = ins*8 + l8;
      gload_lds16(&Ap[(long long)(r0+row)*lda + k0 + l7*8], &As[ins*8][0]);
    }
    #pragma unroll
    for (int i=0;i<BN/32;i++){
      int ins = wave + 4*i;
      int row = ins*8 + l8;
      gload_lds16(&Bp[(long long)(c0+row)*ldb + k0 + l7*8], &Bs[ins*8][0]);
    }
    __syncthreads();  // compiler drains vmcnt(0) before barrier
    #pragma unroll
    for (int ks=0; ks<2; ++ks){
      short8 af[FM], bfr[FN];
      #pragma unroll
      for (int m=0;m<FM;m++) af[m] = *(const short8*)&As[wr + m*16 + fr][ks*32 + fk*8];
      #pragma unroll
      for (int n=0;n<FN;n++) bfr[n] = *(const short8*)&Bs[wc + n*16 + fr][ks*32 + fk*8];
      #pragma unroll
      for (int m=0;m<FM;m++)
        #pragma unroll
        for (int n=0;n<FN;n++)
          acc[m][n] = __builtin_amdgcn_mfma_f32_16x16x32_bf16(af[m], bfr[n], acc[m][n], 0,0,0);
    }
  }

  float yscale = 0.f;
  if constexpr (EPI==EPI_YADD) yscale = 1.f/(1.f+expf(-logit[0]));

  #pragma unroll
  for (int m=0;m<FM;m++)
   #pragma unroll
   for (int n=0;n<FN;n++)
    #pragma unroll
    for (int j=0;j<4;j++){
      int r = r0 + wr + m*16 + fk*4 + j;
      int c = c0 + wc + n*16 + fr;
      float v = acc[m][n][j];
      if constexpr (EPI==EPI_F32){
        ((float*)p0)[(long long)z*sC + (long long)r*ldc + c] = v;
      } else if constexpr (EPI==EPI_BF16){
        ((u16*)p0)[(long long)z*sC + (long long)r*ldc + c] = f2bf(v);
      } else if constexpr (EPI==EPI_LOGBF16){
        ((u16*)p0)[(long long)z*sC + (long long)r*ldc + c] = f2bf(__logf(v + 1e-6f));
      } else if constexpr (EPI==EPI_BF16T){
        ((u16*)p0)[(long long)z*sC + (long long)c*ldc + r] = f2bf(v);
      } else if constexpr (EPI==EPI_QKV){
        int b = r>>10, n_ = r&1023;
        int which = c>>9, h = (c>>6)&7, d = c&63;
        long long bh = (long long)b*8 + h;
        if (which==0)      ((u16*)p0)[(bh*1024 + n_)*64 + d] = f2bf(v*0.125f);
        else if (which==1) ((u16*)p1)[(bh*1024 + n_)*64 + d] = f2bf(v);
        else               ((u16*)p2)[(bh*64 + d)*1024 + n_] = f2bf(v);
      } else if constexpr (EPI==EPI_Y){
        int b = z>>3, h = z&7;
        ((float*)p0)[((long long)(b*1024 + r))*512 + h*64 + c] = v;
      } else if constexpr (EPI==EPI_YADD){
        int b = z>>3, h = z&7;
        ((float*)p0)[((long long)(b*1024 + r))*512 + h*64 + c] += yscale*v;
      }
    }
}

// row softmax over 1024 cols; src f32 or bf16; dst bf16
template<int SRC_BF16>
__global__ __launch_bounds__(256) void softmax_rows(const void* __restrict__ Sv, u16* __restrict__ A)
{
  const long long row = blockIdx.x;
  const int tid = threadIdx.x;
  float v[4];
  if constexpr (SRC_BF16){
    const u16* s = (const u16*)Sv + row*1024;
    short4v x = *(const short4v*)&s[tid*4];
    #pragma unroll
    for (int i=0;i<4;i++) v[i] = bf2f((u16)x[i]);
  } else {
    const float* s = (const float*)Sv + row*1024;
    f32x4 x = *(const f32x4*)&s[tid*4];
    #pragma unroll
    for (int i=0;i<4;i++) v[i] = x[i];
  }
  __shared__ float red[4];
  float m = fmaxf(fmaxf(v[0],v[1]),fmaxf(v[2],v[3]));
  #pragma unroll
  for (int off=32; off>0; off>>=1) m = fmaxf(m, __shfl_xor(m, off, 64));
  if ((tid&63)==0) red[tid>>6] = m;
  __syncthreads();
  m = fmaxf(fmaxf(red[0],red[1]),fmaxf(red[2],red[3]));
  float e[4], sum=0.f;
  #pragma unroll
  for (int i=0;i<4;i++){ e[i] = __expf(v[i]-m); sum += e[i]; }
  #pragma unroll
  for (int off=32; off>0; off>>=1) sum += __shfl_xor(sum, off, 64);
  __syncthreads();
  if ((tid&63)==0) red[tid>>6] = sum;
  __syncthreads();
  float inv = 1.f/(red[0]+red[1]+red[2]+red[3]);
  u16* a = A + row*1024;
  short4v o;
  #pragma unroll
  for (int i=0;i<4;i++) o[i] = (short)f2bf(e[i]*inv);
  *(short4v*)&a[tid*4] = o;
}

// 1024x1024 bf16 transpose per z
__global__ __launch_bounds__(256) void transpose_bf16(const u16* __restrict__ in, u16* __restrict__ out)
{
  __shared__ u16 tile[32][33];
  const long long base = (long long)blockIdx.z*1024*1024;
  const int xb = blockIdx.x*32, yb = blockIdx.y*32;
  const int tx = threadIdx.x&31, ty = threadIdx.x>>5;
  #pragma unroll
  for (int rr=0;rr<4;rr++){
    int i = ty + rr*8;
    tile[i][tx] = in[base + (long long)(yb+i)*1024 + xb+tx];
  }
  __syncthreads();
  #pragma unroll
  for (int rr=0;rr<4;rr++){
    int i = ty + rr*8;
    out[base + (long long)(xb+i)*1024 + yb+tx] = tile[tx][i];
  }
}

__global__ __launch_bounds__(256) void cast_f32_bf16(const float* __restrict__ in, u16* __restrict__ out, int n4)
{
  int i = blockIdx.x*256 + threadIdx.x;
  if (i < n4){
    f32x4 x = ((const f32x4*)in)[i];
    short4v o;
    #pragma unroll
    for (int j=0;j<4;j++) o[j] = (short)f2bf(x[j]);
    ((short4v*)out)[i] = o;
  }
}

// out[c][r] = bf16(in[r][c]); in: rows x cols (f32)
__global__ __launch_bounds__(256) void castT_f32_bf16(const float* __restrict__ in, u16* __restrict__ out, int rows, int cols)
{
  __shared__ float tile[32][33];
  const int cb = blockIdx.x*32, rb = blockIdx.y*32;
  const int tx = threadIdx.x&31, ty = threadIdx.x>>5;
  #pragma unroll
  for (int rr=0;rr<4;rr++){
    int i = ty + rr*8;
    tile[i][tx] = in[(long long)(rb+i)*cols + cb+tx];
  }
  __syncthreads();
  #pragma unroll
  for (int rr=0;rr<4;rr++){
    int i = ty + rr*8;
    out[(long long)(cb+i)*rows + rb+tx] = f2bf(tile[tx][i]);
  }
}

// gating + Smix -> Smix bf16. Weights read with thread-invariant indices from
// GLOBAL pointers -> compiler emits s_load into SGPRs (SMEM pipe, per-wave).
// R7 was ds_read-bound: ~96 LDS broadcast reads/element = ~238us.
__global__ __launch_bounds__(256) void gating_kernel(
    const u16* __restrict__ S0, const u16* __restrict__ S1,
    const u16* __restrict__ CR, const u16* __restrict__ CL,
    const float* __restrict__ w1, const float* __restrict__ b1,
    const float* __restrict__ w2, const float* __restrict__ b2,
    u16* __restrict__ Smix)
{
  __shared__ float t0[32][33], t1[32][33], t0t[32][33], t1t[32][33];
  const int tid = threadIdx.x;
  const long long base = (long long)blockIdx.z*1024*1024;
  const int rb = blockIdx.y*32, cb = blockIdx.x*32;
  const int tx = tid&31, ty = tid>>5;
  #pragma unroll
  for (int rr=0;rr<4;rr++){
    int i = ty + rr*8;
    t0 [i][tx] = bf2f(S0[base + (long long)(rb+i)*1024 + cb+tx]);
    t1 [i][tx] = bf2f(S1[base + (long long)(rb+i)*1024 + cb+tx]);
    t0t[i][tx] = bf2f(S0[base + (long long)(cb+i)*1024 + rb+tx]);
    t1t[i][tx] = bf2f(S1[base + (long long)(cb+i)*1024 + rb+tx]);
  }
  __syncthreads();
  #pragma unroll 1
  for (int rr=0;rr<4;rr++){
    int i = ty + rr*8;
    float s0  = t0[i][tx], s1v = t1[i][tx];
    float s0t = t0t[tx][i], s1t = t1t[tx][i];
    long long off = base + (long long)(rb+i)*1024 + cb+tx;
    float cr = bf2f(CR[off]), cl = bf2f(CL[off]);
    float a0 = b2[0], a1 = b2[1], a2 = b2[2], a3 = b2[3];
    #pragma unroll 4
    for (int o=0;o<16;o++){
      float xx = b1[o] + w1[o*6+0]*s0 + w1[o*6+1]*s1v + w1[o*6+2]*s0t
               + w1[o*6+3]*s1t + w1[o*6+4]*cr + w1[o*6+5]*cl;
      float z = 1.5957691216057308f*(xx + 0.044715f*xx*xx*xx);
      float hh = xx * fsigmoid(z);
      a0 += w2[o]*hh; a1 += w2[16+o]*hh; a2 += w2[32+o]*hh; a3 += w2[48+o]*hh;
    }
    float g0 = fsigmoid(a0), g1 = fsigmoid(a1), g2 = fsigmoid(a2), g3 = fsigmoid(a3);
    float mx = fmaxf(s0,s1v);
    float e = __expf(-fabsf(s0-s1v));
    float lse = mx + __logf(1.f + e);
    float smix = s0 + g0*s1v + g1*(lse-s0) - g2*(0.5f*s1v) + g3*cr;
    Smix[off] = f2bf(smix);
  }
}

extern "C" void kernel_launch(void* const* d_in, const int* in_sizes, int n_in,
                              void* d_out, int out_size, void* d_ws, size_t ws_size,
                              hipStream_t stream)
{
  const float* x     = (const float*)d_in[0];
  const float* Wqkv0 = (const float*)d_in[1];
  const float* Wqkv1 = (const float*)d_in[2];
  const float* Wproj = (const float*)d_in[3];
  const float* c1w   = (const float*)d_in[4];
  const float* c1b   = (const float*)d_in[5];
  const float* c2w   = (const float*)d_in[6];
  const float* c2b   = (const float*)d_in[7];
  const float* logit = (const float*)d_in[8];

  char* ws = (char*)d_ws;
  size_t off = 0;
  auto alloc = [&](size_t bytes)->char*{ char* p = ws + off; off = (off + bytes + 255) & ~(size_t)255; return p; };

  const long long NN16 = 16LL*1024*1024;
  u16* xb  = (u16*)alloc(2048LL*512*2);
  u16* w0T = (u16*)alloc(1536LL*512*2);
  u16* w1T = (u16*)alloc(1536LL*512*2);
  u16* wpT = (u16*)alloc(512LL*512*2);
  u16* q0  = (u16*)alloc(16LL*1024*64*2);
  u16* k0  = (u16*)alloc(16LL*1024*64*2);
  u16* v0T = (u16*)alloc(16LL*1024*64*2);
  u16* q1  = (u16*)alloc(16LL*1024*64*2);
  u16* k1  = (u16*)alloc(16LL*1024*64*2);
  u16* v1T = (u16*)alloc(16LL*1024*64*2);
  u16* S0b = (u16*)alloc(NN16*2);   // reused as Ab after gating
  u16* S1b = (u16*)alloc(NN16*2);
  u16* A0  = (u16*)alloc(NN16*2);
  u16* A1  = (u16*)alloc(NN16*2);
  u16* A0T = (u16*)alloc(NN16*2);   // reused as CR after CL GEMM
  u16* A1T = (u16*)alloc(NN16*2);   // reused as Smix after CR GEMM
  u16* CL  = (u16*)alloc(NN16*2);
  u16* tT  = (u16*)alloc(16LL*64*1024*2);
  float* Y = (float*)alloc(2048LL*512*4);
  u16* Yb  = (u16*)alloc(2048LL*512*2);

  u16* CR   = A0T;
  u16* Smix = A1T;
  u16* Ab   = S0b;

  if (off > ws_size){
    fprintf(stderr, "kernel_launch: ws too small: need %zu have %zu\n", off, ws_size);
    return;
  }

  dim3 blk(256);

  // 1. input casts / transposed weight casts
  cast_f32_bf16<<<dim3(262144/256), blk, 0, stream>>>(x, xb, 262144);
  castT_f32_bf16<<<dim3(48,16), blk, 0, stream>>>(Wqkv0, w0T, 512, 1536);
  castT_f32_bf16<<<dim3(48,16), blk, 0, stream>>>(Wqkv1, w1T, 512, 1536);
  castT_f32_bf16<<<dim3(16,16), blk, 0, stream>>>(Wproj, wpT, 512, 512);

  // 2. QKV projections
  gemm_bt<128,128,2,2,EPI_QKV><<<dim3(12,16,1), blk, 0, stream>>>(
      xb, w0T, q0, k0, v0T, nullptr, 512, 512, 512, 0,0, 0,0);
  gemm_bt<128,128,2,2,EPI_QKV><<<dim3(12,16,1), blk, 0, stream>>>(
      xb, w1T, q1, k1, v1T, nullptr, 512, 512, 512, 0,0, 0,0);

  // 3. S0, S1
  gemm_bt<128,128,2,2,EPI_BF16><<<dim3(8,8,16), blk, 0, stream>>>(
      q0, k0, S0b, nullptr, nullptr, nullptr, 64, 64, 64, 65536,65536, 1048576, 1024);
  gemm_bt<128,128,2,2,EPI_BF16><<<dim3(8,8,16), blk, 0, stream>>>(
      q1, k1, S1b, nullptr, nullptr, nullptr, 64, 64, 64, 65536,65536, 1048576, 1024);

  // 4. softmaxes
  softmax_rows<1><<<dim3(16384), blk, 0, stream>>>(S0b, A0);
  softmax_rows<1><<<dim3(16384), blk, 0, stream>>>(S1b, A1);

  // 5. transposes
  transpose_bf16<<<dim3(32,32,16), blk, 0, stream>>>(A0, A0T);
  transpose_bf16<<<dim3(32,32,16), blk, 0, stream>>>(A1, A1T);

  // 6. Cli then Cri (frees A0T for CR)
  gemm_bt<128,128,2,2,EPI_LOGBF16><<<dim3(8,8,16), blk, 0, stream>>>(
      A1, A0T, CL, nullptr, nullptr, nullptr, 1024, 1024, 1024, 1048576,1048576, 1048576, 1024);
  gemm_bt<128,128,2,2,EPI_LOGBF16><<<dim3(8,8,16), blk, 0, stream>>>(
      A0, A1T, CR, nullptr, nullptr, nullptr, 1024, 1024, 1024, 1048576,1048576, 1048576, 1024);

  // 7. gating -> Smix
  gating_kernel<<<dim3(32,32,16), blk, 0, stream>>>(S0b, S1b, CR, CL, c1w, c1b, c2w, c2b, Smix);

  // 8. A = softmax(Smix)
  softmax_rows<1><<<dim3(16384), blk, 0, stream>>>(Smix, Ab);

  // 9. t = A1@v1 (tT), y = A@v0, y += sig*A0@t
  gemm_bt<64,64,2,2,EPI_BF16T><<<dim3(1,16,16), blk, 0, stream>>>(
      A1, v1T, tT, nullptr, nullptr, nullptr, 1024, 1024, 1024, 1048576,65536, 65536, 1024);
  gemm_bt<64,64,2,2,EPI_Y><<<dim3(1,16,16), blk, 0, stream>>>(
      Ab, v0T, Y, nullptr, nullptr, nullptr, 1024, 1024, 1024, 1048576,65536, 0, 0);
  gemm_bt<64,64,2,2,EPI_YADD><<<dim3(1,16,16), blk, 0, stream>>>(
      A0, tT, Y, nullptr, nullptr, logit, 1024, 1024, 1024, 1048576,65536, 0, 0);

  // 10. out = Y @ Wproj
  cast_f32_bf16<<<dim3(262144/256), blk, 0, stream>>>(Y, Yb, 262144);
  gemm_bt<64,64,2,2,EPI_F32><<<dim3(8,32,1), blk, 0, stream>>>(
      Yb, wpT, d_out, nullptr, nullptr, nullptr, 512, 512, 512, 0,0, 0, 512);

  (void)in_sizes; (void)n_in; (void)out_size;
}